// Round 1
// baseline (662.277 us; speedup 1.0000x reference)
//
#include <hip/hip_runtime.h>

// Problem: TV Chambolle, image (8, 2048, 128) f32, 29 update iters + final div.
// Layout: v = (b*2048 + t)*128 + f.  Axis strides: B: 262144, T: 128, F: 1.

#define BB 8
#define TT 2048
#define FF 128
#define NV (BB*TT*FF)        // 2,097,152
#define SB (TT*FF)           // 262144
#define ST FF                // 128

constexpr float TAU = 1.0f / 6.0f;

// out(w) = x(w) + div(p)(w), computed on the fly from p planes.
__device__ __forceinline__ float out_at(const float* __restrict__ x,
                                        const float* __restrict__ p0,
                                        const float* __restrict__ p1,
                                        const float* __restrict__ p2,
                                        int v, int b, int t, int f) {
    float d = x[v] - p0[v] - p1[v] - p2[v];
    if (b > 0) d += p0[v - SB];
    if (t > 0) d += p1[v - ST];
    if (f > 0) d += p2[v - 1];
    return d;
}

// Fused per-iteration update: p_out = (p_in - TAU*grad(out)) / (|grad(out)|*TAU/lam + 1)
__global__ __launch_bounds__(256)
void k_update_fused(const float* __restrict__ x,
                    const float* __restrict__ pin,
                    float* __restrict__ pout,
                    const float* __restrict__ lam) {
    int v = blockIdx.x * 256 + threadIdx.x;
    int f = v & (FF - 1);
    int t = (v >> 7) & (TT - 1);
    int b = v >> 18;
    const float* p0 = pin;
    const float* p1 = pin + NV;
    const float* p2 = pin + 2 * NV;

    float p0v = p0[v], p1v = p1[v], p2v = p2[v];
    float outc = x[v] - p0v - p1v - p2v;
    if (b > 0) outc += p0[v - SB];
    if (t > 0) outc += p1[v - ST];
    if (f > 0) outc += p2[v - 1];

    float gB = 0.f, gT = 0.f, gF = 0.f;
    if (b < BB - 1) gB = out_at(x, p0, p1, p2, v + SB, b + 1, t, f) - outc;
    if (t < TT - 1) gT = out_at(x, p0, p1, p2, v + ST, b, t + 1, f) - outc;
    if (f < FF - 1) gF = out_at(x, p0, p1, p2, v + 1, b, t, f + 1) - outc;

    float norm = sqrtf(gB * gB + gT * gT + gF * gF);
    float s = TAU / lam[0];
    float r = 1.0f / (norm * s + 1.0f);
    pout[v]          = (p0v - TAU * gB) * r;
    pout[v + NV]     = (p1v - TAU * gT) * r;
    pout[v + 2 * NV] = (p2v - TAU * gF) * r;
}

// ---- fallback path (ws too small for double-buffered p): materialize out ----
__global__ __launch_bounds__(256)
void k_out(const float* __restrict__ x,
           const float* __restrict__ pin,
           float* __restrict__ outb) {
    int v = blockIdx.x * 256 + threadIdx.x;
    int f = v & (FF - 1);
    int t = (v >> 7) & (TT - 1);
    int b = v >> 18;
    outb[v] = out_at(x, pin, pin + NV, pin + 2 * NV, v, b, t, f);
}

__global__ __launch_bounds__(256)
void k_update_inplace(const float* __restrict__ outb,
                      float* __restrict__ p,
                      const float* __restrict__ lam) {
    int v = blockIdx.x * 256 + threadIdx.x;
    int f = v & (FF - 1);
    int t = (v >> 7) & (TT - 1);
    int b = v >> 18;
    float outc = outb[v];
    float gB = (b < BB - 1) ? outb[v + SB] - outc : 0.f;
    float gT = (t < TT - 1) ? outb[v + ST] - outc : 0.f;
    float gF = (f < FF - 1) ? outb[v + 1] - outc : 0.f;
    float norm = sqrtf(gB * gB + gT * gT + gF * gF);
    float s = TAU / lam[0];
    float r = 1.0f / (norm * s + 1.0f);
    p[v]          = (p[v] - TAU * gB) * r;           // safe: reads only own voxel
    p[v + NV]     = (p[v + NV] - TAU * gT) * r;
    p[v + 2 * NV] = (p[v + 2 * NV] - TAU * gF) * r;
}

__global__ __launch_bounds__(256)
void k_final(const float* __restrict__ x,
             const float* __restrict__ pin,
             const float* __restrict__ bias,
             float* __restrict__ out) {
    int v = blockIdx.x * 256 + threadIdx.x;
    int f = v & (FF - 1);
    int t = (v >> 7) & (TT - 1);
    int b = v >> 18;
    out[v] = out_at(x, pin, pin + NV, pin + 2 * NV, v, b, t, f) + bias[f];
}

extern "C" void kernel_launch(void* const* d_in, const int* in_sizes, int n_in,
                              void* d_out, int out_size, void* d_ws, size_t ws_size,
                              hipStream_t stream) {
    const float* x    = (const float*)d_in[0];
    const float* lam  = (const float*)d_in[1];
    const float* bias = (const float*)d_in[2];
    float* out = (float*)d_out;

    const int nblk = NV / 256;               // 8192
    const int ITERS = 29;                    // MAX_ITERS - 1

    if (ws_size >= (size_t)(6 * NV) * sizeof(float)) {
        // double-buffered p: pA | pB, 24 MB each
        float* pA = (float*)d_ws;
        float* pB = pA + 3 * NV;
        hipMemsetAsync(pA, 0, (size_t)(3 * NV) * sizeof(float), stream);
        float* pin = pA;
        float* pout = pB;
        for (int i = 0; i < ITERS; ++i) {
            k_update_fused<<<nblk, 256, 0, stream>>>(x, pin, pout, lam);
            float* tmp = pin; pin = pout; pout = tmp;
        }
        k_final<<<nblk, 256, 0, stream>>>(x, pin, bias, out);
    } else {
        // single p buffer + out buffer (32 MB total)
        float* p = (float*)d_ws;
        float* outb = p + 3 * NV;
        hipMemsetAsync(p, 0, (size_t)(3 * NV) * sizeof(float), stream);
        for (int i = 0; i < ITERS; ++i) {
            k_out<<<nblk, 256, 0, stream>>>(x, p, outb);
            k_update_inplace<<<nblk, 256, 0, stream>>>(outb, p, lam);
        }
        k_final<<<nblk, 256, 0, stream>>>(x, p, bias, out);
    }
}

// Round 2
// 510.317 us; speedup vs baseline: 1.2978x; 1.2978x over previous
//
#include <hip/hip_runtime.h>

// TV Chambolle, image (8, 2048, 128) f32: 29 p-updates + final out = x + div(p) + bias.
// v = b*SB + t*ST + f.  Block tile: all 8 b-planes x 4 t-rows x 128 f.
// Phase 1: compute out = x + div(p) ONCE per tile voxel (+1 t-halo row) -> LDS.
// Phase 2: grads from LDS/regs, update p. float4 everywhere.

#define BB 8
#define TT 2048
#define FF 128
#define NV (BB*TT*FF)        // 2,097,152
#define SB (TT*FF)           // 262144
#define ST FF                // 128
#define TT4 4                // t-rows per block

constexpr float TAU = 1.0f / 6.0f;

__device__ __forceinline__ float4 ld4(const float* p) { return *reinterpret_cast<const float4*>(p); }
__device__ __forceinline__ void st4(float* p, const float4& v) { *reinterpret_cast<float4*>(p) = v; }

// out = x - (p0+p1+p2) + p0[v-SB] + p1[v-ST] + p2[v-1]   (terms dropped at lower edges)
__device__ __forceinline__ float4 compute_out(const float* __restrict__ x,
                                              const float* __restrict__ p0,
                                              const float* __restrict__ p1,
                                              const float* __restrict__ p2,
                                              int v, int b, int t, int f0,
                                              float4& a0, float4& a1, float4& a2) {
    float4 X = ld4(x + v);
    a0 = ld4(p0 + v); a1 = ld4(p1 + v); a2 = ld4(p2 + v);
    float ox = X.x - a0.x - a1.x - a2.x;
    float oy = X.y - a0.y - a1.y - a2.y;
    float oz = X.z - a0.z - a1.z - a2.z;
    float ow = X.w - a0.w - a1.w - a2.w;
    if (b > 0) { float4 h = ld4(p0 + v - SB); ox += h.x; oy += h.y; oz += h.z; ow += h.w; }
    if (t > 0) { float4 h = ld4(p1 + v - ST); ox += h.x; oy += h.y; oz += h.z; ow += h.w; }
    if (f0 > 0) ox += p2[v - 1];
    oy += a2.x; oz += a2.y; ow += a2.z;
    return make_float4(ox, oy, oz, ow);
}

// Generic iteration: pout = (pin - TAU*grad(out)) / (|grad(out)|*TAU/lam + 1)
__global__ __launch_bounds__(256)
void k_iter(const float* __restrict__ x, const float* __restrict__ pin,
            float* __restrict__ pout, const float* __restrict__ lam) {
    __shared__ __align__(16) float outl[BB * (TT4 + 1) * FF];   // 20 KB
    const int tid = threadIdx.x;
    const int t0  = blockIdx.x * TT4;
    const float s = TAU / lam[0];
    const float* p0 = pin;
    const float* p1 = pin + NV;
    const float* p2 = pin + 2 * NV;

    const int f0 = (tid & 31) * 4;
    const int r  = (tid >> 5) & 3;
    const int b0 = tid >> 7;                 // 0 or 1
    const int t  = t0 + r;

    float4 A0[4], A1[4], A2[4], C[4];

    // ---- phase 1: out -> LDS (rows r=0..3 via main slots, row 4 via extra slot) ----
    #pragma unroll
    for (int k = 0; k < 4; ++k) {
        const int b = b0 + 2 * k;
        const int v = b * SB + t * ST + f0;
        float4 o = compute_out(x, p0, p1, p2, v, b, t, f0, A0[k], A1[k], A2[k]);
        C[k] = o;
        st4(&outl[(b * (TT4 + 1) + r) * FF + f0], o);
    }
    {
        const int be = tid >> 5;             // 0..7
        const int fe0 = (tid & 31) * 4;
        const int te = t0 + TT4;
        if (te < TT) {
            const int v = be * SB + te * ST + fe0;
            float4 d0, d1, d2;
            float4 o = compute_out(x, p0, p1, p2, v, be, te, fe0, d0, d1, d2);
            st4(&outl[(be * (TT4 + 1) + TT4) * FF + fe0], o);
        }
    }
    __syncthreads();

    // ---- phase 2: grads from LDS/regs, update p ----
    #pragma unroll
    for (int k = 0; k < 4; ++k) {
        const int b = b0 + 2 * k;
        const int v = b * SB + t * ST + f0;
        const float4 c = C[k];

        float4 gB = make_float4(0.f, 0.f, 0.f, 0.f);
        if (b < BB - 1) {
            float4 n = *reinterpret_cast<const float4*>(&outl[((b + 1) * (TT4 + 1) + r) * FF + f0]);
            gB = make_float4(n.x - c.x, n.y - c.y, n.z - c.z, n.w - c.w);
        }
        float4 gT = make_float4(0.f, 0.f, 0.f, 0.f);
        if (t < TT - 1) {
            float4 n = *reinterpret_cast<const float4*>(&outl[(b * (TT4 + 1) + r + 1) * FF + f0]);
            gT = make_float4(n.x - c.x, n.y - c.y, n.z - c.z, n.w - c.w);
        }
        float4 gF;
        gF.x = c.y - c.x;
        gF.y = c.z - c.y;
        gF.z = c.w - c.z;
        gF.w = (f0 < FF - 4) ? (outl[(b * (TT4 + 1) + r) * FF + f0 + 4] - c.w) : 0.f;

        float4 nb;
        nb.x = 1.f / (sqrtf(gB.x * gB.x + gT.x * gT.x + gF.x * gF.x) * s + 1.f);
        nb.y = 1.f / (sqrtf(gB.y * gB.y + gT.y * gT.y + gF.y * gF.y) * s + 1.f);
        nb.z = 1.f / (sqrtf(gB.z * gB.z + gT.z * gT.z + gF.z * gF.z) * s + 1.f);
        nb.w = 1.f / (sqrtf(gB.w * gB.w + gT.w * gT.w + gF.w * gF.w) * s + 1.f);

        float4 q0, q1, q2;
        q0.x = (A0[k].x - TAU * gB.x) * nb.x;  q0.y = (A0[k].y - TAU * gB.y) * nb.y;
        q0.z = (A0[k].z - TAU * gB.z) * nb.z;  q0.w = (A0[k].w - TAU * gB.w) * nb.w;
        q1.x = (A1[k].x - TAU * gT.x) * nb.x;  q1.y = (A1[k].y - TAU * gT.y) * nb.y;
        q1.z = (A1[k].z - TAU * gT.z) * nb.z;  q1.w = (A1[k].w - TAU * gT.w) * nb.w;
        q2.x = (A2[k].x - TAU * gF.x) * nb.x;  q2.y = (A2[k].y - TAU * gF.y) * nb.y;
        q2.z = (A2[k].z - TAU * gF.z) * nb.z;  q2.w = (A2[k].w - TAU * gF.w) * nb.w;

        st4(pout + v, q0);
        st4(pout + NV + v, q1);
        st4(pout + 2 * NV + v, q2);
    }
}

// First iteration specialized for p == 0: out = x, so p1 = -TAU*grad(x)/(|grad(x)|*s+1).
__global__ __launch_bounds__(256)
void k_first(const float* __restrict__ x, float* __restrict__ pout,
             const float* __restrict__ lam) {
    const int tid = threadIdx.x;
    const int t0  = blockIdx.x * TT4;
    const float s = TAU / lam[0];

    const int f0 = (tid & 31) * 4;
    const int r  = (tid >> 5) & 3;
    const int b0 = tid >> 7;
    const int t  = t0 + r;

    #pragma unroll
    for (int k = 0; k < 4; ++k) {
        const int b = b0 + 2 * k;
        const int v = b * SB + t * ST + f0;
        float4 X = ld4(x + v);

        float4 gB = make_float4(0.f, 0.f, 0.f, 0.f);
        if (b < BB - 1) {
            float4 n = ld4(x + v + SB);
            gB = make_float4(n.x - X.x, n.y - X.y, n.z - X.z, n.w - X.w);
        }
        float4 gT = make_float4(0.f, 0.f, 0.f, 0.f);
        if (t < TT - 1) {
            float4 n = ld4(x + v + ST);
            gT = make_float4(n.x - X.x, n.y - X.y, n.z - X.z, n.w - X.w);
        }
        float4 gF;
        gF.x = X.y - X.x;
        gF.y = X.z - X.y;
        gF.z = X.w - X.z;
        gF.w = (f0 < FF - 4) ? (x[v + 4] - X.w) : 0.f;

        float4 nb;
        nb.x = 1.f / (sqrtf(gB.x * gB.x + gT.x * gT.x + gF.x * gF.x) * s + 1.f);
        nb.y = 1.f / (sqrtf(gB.y * gB.y + gT.y * gT.y + gF.y * gF.y) * s + 1.f);
        nb.z = 1.f / (sqrtf(gB.z * gB.z + gT.z * gT.z + gF.z * gF.z) * s + 1.f);
        nb.w = 1.f / (sqrtf(gB.w * gB.w + gT.w * gT.w + gF.w * gF.w) * s + 1.f);

        float4 q0, q1, q2;
        q0.x = -TAU * gB.x * nb.x;  q0.y = -TAU * gB.y * nb.y;
        q0.z = -TAU * gB.z * nb.z;  q0.w = -TAU * gB.w * nb.w;
        q1.x = -TAU * gT.x * nb.x;  q1.y = -TAU * gT.y * nb.y;
        q1.z = -TAU * gT.z * nb.z;  q1.w = -TAU * gT.w * nb.w;
        q2.x = -TAU * gF.x * nb.x;  q2.y = -TAU * gF.y * nb.y;
        q2.z = -TAU * gF.z * nb.z;  q2.w = -TAU * gF.w * nb.w;

        st4(pout + v, q0);
        st4(pout + NV + v, q1);
        st4(pout + 2 * NV + v, q2);
    }
}

// Final: out = x + div(p) + bias[f]
__global__ __launch_bounds__(256)
void k_final(const float* __restrict__ x, const float* __restrict__ pin,
             const float* __restrict__ bias, float* __restrict__ out) {
    const int gid = blockIdx.x * 256 + threadIdx.x;
    const int v = gid * 4;
    const int f0 = v & (FF - 1);
    const int t = (v >> 7) & (TT - 1);
    const int b = v >> 18;
    float4 d0, d1, d2;
    float4 o = compute_out(x, pin, pin + NV, pin + 2 * NV, v, b, t, f0, d0, d1, d2);
    float4 bi = ld4(bias + f0);
    o.x += bi.x; o.y += bi.y; o.z += bi.z; o.w += bi.w;
    st4(out + v, o);
}

extern "C" void kernel_launch(void* const* d_in, const int* in_sizes, int n_in,
                              void* d_out, int out_size, void* d_ws, size_t ws_size,
                              hipStream_t stream) {
    const float* x    = (const float*)d_in[0];
    const float* lam  = (const float*)d_in[1];
    const float* bias = (const float*)d_in[2];
    float* out = (float*)d_out;

    float* pA = (float*)d_ws;
    float* pB = pA + 3 * NV;

    const int nblk = TT / TT4;               // 512

    // update 1 (p=0 specialization), then 28 generic updates = 29 total
    k_first<<<nblk, 256, 0, stream>>>(x, pA, lam);
    float* pin = pA;
    float* pout = pB;
    for (int i = 0; i < 28; ++i) {
        k_iter<<<nblk, 256, 0, stream>>>(x, pin, pout, lam);
        float* tmp = pin; pin = pout; pout = tmp;
    }
    k_final<<<NV / 1024, 256, 0, stream>>>(x, pin, bias, out);
}

// Round 3
// 487.291 us; speedup vs baseline: 1.3591x; 1.0473x over previous
//
#include <hip/hip_runtime.h>
#include <hip/hip_cooperative_groups.h>

namespace cg = cooperative_groups;

// TV Chambolle, image (8, 2048, 128) f32: 29 p-updates + final out = x + div(p) + bias.
// Persistent cooperative kernel: 512 blocks x 512 threads (2 blocks/CU).
// Block owns t-slab of RR=4 rows x all 8 b x all 128 f. p lives in LDS for all
// 29 iterations; only 1-row t-boundaries are exchanged via global (parity dbuf).
// One grid.sync per iteration (out-halo row recomputed redundantly from the
// right neighbor's published p row).

#define BB 8
#define TT 2048
#define FF 128
#define NV (BB*TT*FF)        // 2,097,152
#define SB (TT*FF)           // 262144
#define ST FF                // 128
#define RR 4                 // t-rows per block
#define NBLK (TT/RR)         // 512
#define NTHR 512
#define PLANE (BB*FF)        // 1024 floats per t-row (all b, all f)

constexpr float TAU = 1.0f / 6.0f;
constexpr int ITERS = 29;    // MAX_ITERS - 1

__device__ __forceinline__ float4 ld4(const float* p) { return *reinterpret_cast<const float4*>(p); }
__device__ __forceinline__ void st4(float* p, const float4& v) { *reinterpret_cast<float4*>(p) = v; }

__global__ __launch_bounds__(NTHR, 4)
void k_persist(const float* __restrict__ x, const float* __restrict__ lam,
               const float* __restrict__ bias, float* __restrict__ out,
               float* __restrict__ pFirst,   // [2][NBLK][3][PLANE]
               float* __restrict__ p1Last)   // [2][NBLK][PLANE]
{
    __shared__ __align__(16) float pL[3 * RR * PLANE];   // 48 KB: p0|p1|p2 tiles
    __shared__ __align__(16) float outL[RR * PLANE];     // 16 KB

    cg::grid_group grid = cg::this_grid();

    const int tid  = threadIdx.x;
    const int blk  = blockIdx.x;
    const int f0   = (tid & 31) * 4;
    const int b    = (tid >> 5) & 7;
    const int rloc = tid >> 8;              // 0 or 1: owns rows {2rloc, 2rloc+1}
    const int t0   = blk * RR;
    const int bf   = b * FF + f0;
    const int r0   = rloc * 2;
    const float s  = TAU / lam[0];

    // zero own p cells
    #pragma unroll
    for (int c = 0; c < 3; ++c) {
        st4(&pL[(c * RR + r0) * PLANE + bf], make_float4(0.f, 0.f, 0.f, 0.f));
        st4(&pL[(c * RR + r0 + 1) * PLANE + bf], make_float4(0.f, 0.f, 0.f, 0.f));
    }
    float4 xr[2];
    xr[0] = ld4(x + b * SB + (t0 + r0) * ST + f0);
    xr[1] = ld4(x + b * SB + (t0 + r0 + 1) * ST + f0);
    __syncthreads();

    float4 a0[2], a1[2], a2[2], o[2];
    float4 oh = make_float4(0.f, 0.f, 0.f, 0.f);
    int par = 0;

    for (int it = 0; it < ITERS; ++it) {
        const bool first = (it == 0);
        const int rd = par ^ 1;             // parity written last iteration

        // ---------- phase 1: out = x + div(p) -> outL ----------
        #pragma unroll
        for (int j = 0; j < 2; ++j) {
            const int r  = r0 + j;
            const int li = r * PLANE + bf;
            a0[j] = ld4(&pL[(0 * RR + r) * PLANE + bf]);
            a1[j] = ld4(&pL[(1 * RR + r) * PLANE + bf]);
            a2[j] = ld4(&pL[(2 * RR + r) * PLANE + bf]);
            float4 oo;
            oo.x = xr[j].x - a0[j].x - a1[j].x - a2[j].x;
            oo.y = xr[j].y - a0[j].y - a1[j].y - a2[j].y + a2[j].x;
            oo.z = xr[j].z - a0[j].z - a1[j].z - a2[j].z + a2[j].y;
            oo.w = xr[j].w - a0[j].w - a1[j].w - a2[j].w + a2[j].z;
            if (b > 0) {
                float4 h = ld4(&pL[(0 * RR + r) * PLANE + bf - FF]);
                oo.x += h.x; oo.y += h.y; oo.z += h.z; oo.w += h.w;
            }
            if (r > 0) {
                float4 h = ld4(&pL[(1 * RR + r - 1) * PLANE + bf]);
                oo.x += h.x; oo.y += h.y; oo.z += h.z; oo.w += h.w;
            } else if (!first && blk > 0) {
                float4 h = ld4(p1Last + (rd * NBLK + blk - 1) * PLANE + bf);
                oo.x += h.x; oo.y += h.y; oo.z += h.z; oo.w += h.w;
            }
            if (f0 > 0) oo.x += pL[(2 * RR + r) * PLANE + bf - 1];
            o[j] = oo;
            st4(&outL[li], oo);
        }

        // out-halo row t0+RR (register-held, rloc==1 threads only)
        if (rloc == 1 && blk < NBLK - 1) {
            float4 xh = ld4(x + b * SB + (t0 + RR) * ST + f0);
            if (first) {
                oh = xh;
            } else {
                const float* pb = pFirst + (rd * NBLK + blk + 1) * 3 * PLANE;
                float4 q0 = ld4(pb + 0 * PLANE + bf);
                float4 q1 = ld4(pb + 1 * PLANE + bf);
                float4 q2 = ld4(pb + 2 * PLANE + bf);
                oh.x = xh.x - q0.x - q1.x - q2.x;
                oh.y = xh.y - q0.y - q1.y - q2.y + q2.x;
                oh.z = xh.z - q0.z - q1.z - q2.z + q2.y;
                oh.w = xh.w - q0.w - q1.w - q2.w + q2.z;
                if (b > 0) {
                    float4 h = ld4(pb + 0 * PLANE + bf - FF);
                    oh.x += h.x; oh.y += h.y; oh.z += h.z; oh.w += h.w;
                }
                // + p1[t0+RR-1] = own p1 row 3 (in registers)
                oh.x += a1[1].x; oh.y += a1[1].y; oh.z += a1[1].z; oh.w += a1[1].w;
                if (f0 > 0) oh.x += pb[2 * PLANE + bf - 1];
            }
        }
        __syncthreads();

        // ---------- phase 2: grads, p update (in-place, own cells) ----------
        #pragma unroll
        for (int j = 0; j < 2; ++j) {
            const int r  = r0 + j;
            const int li = r * PLANE + bf;
            const float4 c = o[j];
            float4 gB = make_float4(0.f, 0.f, 0.f, 0.f);
            if (b < BB - 1) {
                float4 n = ld4(&outL[r * PLANE + bf + FF]);
                gB.x = n.x - c.x; gB.y = n.y - c.y; gB.z = n.z - c.z; gB.w = n.w - c.w;
            }
            float4 gT = make_float4(0.f, 0.f, 0.f, 0.f);
            if (r < RR - 1) {
                float4 n = ld4(&outL[(r + 1) * PLANE + bf]);
                gT.x = n.x - c.x; gT.y = n.y - c.y; gT.z = n.z - c.z; gT.w = n.w - c.w;
            } else if (blk < NBLK - 1) {     // r==RR-1 -> rloc==1 -> oh valid
                gT.x = oh.x - c.x; gT.y = oh.y - c.y; gT.z = oh.z - c.z; gT.w = oh.w - c.w;
            }
            float4 gF;
            gF.x = c.y - c.x;
            gF.y = c.z - c.y;
            gF.z = c.w - c.z;
            gF.w = (f0 < FF - 4) ? (outL[li + 4] - c.w) : 0.f;

            float4 nb;
            nb.x = 1.f / (sqrtf(gB.x * gB.x + gT.x * gT.x + gF.x * gF.x) * s + 1.f);
            nb.y = 1.f / (sqrtf(gB.y * gB.y + gT.y * gT.y + gF.y * gF.y) * s + 1.f);
            nb.z = 1.f / (sqrtf(gB.z * gB.z + gT.z * gT.z + gF.z * gF.z) * s + 1.f);
            nb.w = 1.f / (sqrtf(gB.w * gB.w + gT.w * gT.w + gF.w * gF.w) * s + 1.f);

            float4 q0, q1, q2;
            q0.x = (a0[j].x - TAU * gB.x) * nb.x;  q0.y = (a0[j].y - TAU * gB.y) * nb.y;
            q0.z = (a0[j].z - TAU * gB.z) * nb.z;  q0.w = (a0[j].w - TAU * gB.w) * nb.w;
            q1.x = (a1[j].x - TAU * gT.x) * nb.x;  q1.y = (a1[j].y - TAU * gT.y) * nb.y;
            q1.z = (a1[j].z - TAU * gT.z) * nb.z;  q1.w = (a1[j].w - TAU * gT.w) * nb.w;
            q2.x = (a2[j].x - TAU * gF.x) * nb.x;  q2.y = (a2[j].y - TAU * gF.y) * nb.y;
            q2.z = (a2[j].z - TAU * gF.z) * nb.z;  q2.w = (a2[j].w - TAU * gF.w) * nb.w;

            st4(&pL[(0 * RR + r) * PLANE + bf], q0);
            st4(&pL[(1 * RR + r) * PLANE + bf], q1);
            st4(&pL[(2 * RR + r) * PLANE + bf], q2);

            if (r == 0) {                   // publish new p row 0 (all comps)
                float* pb = pFirst + (par * NBLK + blk) * 3 * PLANE;
                st4(pb + 0 * PLANE + bf, q0);
                st4(pb + 1 * PLANE + bf, q1);
                st4(pb + 2 * PLANE + bf, q2);
            }
            if (r == RR - 1) {              // publish new p1 last row
                st4(p1Last + (par * NBLK + blk) * PLANE + bf, q1);
            }
        }
        grid.sync();
        par ^= 1;
    }

    // ---------- epilogue: out = x + div(p) + bias ----------
    {
        const int rd = par ^ 1;             // parity of the last writes
        float4 bi = ld4(bias + f0);
        #pragma unroll
        for (int j = 0; j < 2; ++j) {
            const int r = r0 + j;
            float4 A0 = ld4(&pL[(0 * RR + r) * PLANE + bf]);
            float4 A1 = ld4(&pL[(1 * RR + r) * PLANE + bf]);
            float4 A2 = ld4(&pL[(2 * RR + r) * PLANE + bf]);
            float4 oo;
            oo.x = xr[j].x - A0.x - A1.x - A2.x;
            oo.y = xr[j].y - A0.y - A1.y - A2.y + A2.x;
            oo.z = xr[j].z - A0.z - A1.z - A2.z + A2.y;
            oo.w = xr[j].w - A0.w - A1.w - A2.w + A2.z;
            if (b > 0) {
                float4 h = ld4(&pL[(0 * RR + r) * PLANE + bf - FF]);
                oo.x += h.x; oo.y += h.y; oo.z += h.z; oo.w += h.w;
            }
            if (r > 0) {
                float4 h = ld4(&pL[(1 * RR + r - 1) * PLANE + bf]);
                oo.x += h.x; oo.y += h.y; oo.z += h.z; oo.w += h.w;
            } else if (blk > 0) {
                float4 h = ld4(p1Last + (rd * NBLK + blk - 1) * PLANE + bf);
                oo.x += h.x; oo.y += h.y; oo.z += h.z; oo.w += h.w;
            }
            if (f0 > 0) oo.x += pL[(2 * RR + r) * PLANE + bf - 1];
            oo.x += bi.x; oo.y += bi.y; oo.z += bi.z; oo.w += bi.w;
            st4(out + b * SB + (t0 + r) * ST + f0, oo);
        }
    }
}

// ==================== fallback path (R2 kernels, proven) ====================
#define TT4 4

__device__ __forceinline__ float4 compute_out_g(const float* __restrict__ x,
                                                const float* __restrict__ p0,
                                                const float* __restrict__ p1,
                                                const float* __restrict__ p2,
                                                int v, int b, int t, int f0,
                                                float4& a0, float4& a1, float4& a2) {
    float4 X = ld4(x + v);
    a0 = ld4(p0 + v); a1 = ld4(p1 + v); a2 = ld4(p2 + v);
    float ox = X.x - a0.x - a1.x - a2.x;
    float oy = X.y - a0.y - a1.y - a2.y;
    float oz = X.z - a0.z - a1.z - a2.z;
    float ow = X.w - a0.w - a1.w - a2.w;
    if (b > 0) { float4 h = ld4(p0 + v - SB); ox += h.x; oy += h.y; oz += h.z; ow += h.w; }
    if (t > 0) { float4 h = ld4(p1 + v - ST); ox += h.x; oy += h.y; oz += h.z; ow += h.w; }
    if (f0 > 0) ox += p2[v - 1];
    oy += a2.x; oz += a2.y; ow += a2.z;
    return make_float4(ox, oy, oz, ow);
}

__global__ __launch_bounds__(256)
void k_iter(const float* __restrict__ x, const float* __restrict__ pin,
            float* __restrict__ pout, const float* __restrict__ lam) {
    __shared__ __align__(16) float outl[BB * (TT4 + 1) * FF];
    const int tid = threadIdx.x;
    const int t0  = blockIdx.x * TT4;
    const float s = TAU / lam[0];
    const float* p0 = pin;
    const float* p1 = pin + NV;
    const float* p2 = pin + 2 * NV;
    const int f0 = (tid & 31) * 4;
    const int r  = (tid >> 5) & 3;
    const int b0 = tid >> 7;
    const int t  = t0 + r;
    float4 A0[4], A1[4], A2[4], C[4];
    #pragma unroll
    for (int k = 0; k < 4; ++k) {
        const int b = b0 + 2 * k;
        const int v = b * SB + t * ST + f0;
        float4 o = compute_out_g(x, p0, p1, p2, v, b, t, f0, A0[k], A1[k], A2[k]);
        C[k] = o;
        st4(&outl[(b * (TT4 + 1) + r) * FF + f0], o);
    }
    {
        const int be = tid >> 5;
        const int fe0 = (tid & 31) * 4;
        const int te = t0 + TT4;
        if (te < TT) {
            const int v = be * SB + te * ST + fe0;
            float4 d0, d1, d2;
            float4 o = compute_out_g(x, p0, p1, p2, v, be, te, fe0, d0, d1, d2);
            st4(&outl[(be * (TT4 + 1) + TT4) * FF + fe0], o);
        }
    }
    __syncthreads();
    #pragma unroll
    for (int k = 0; k < 4; ++k) {
        const int b = b0 + 2 * k;
        const int v = b * SB + t * ST + f0;
        const float4 c = C[k];
        float4 gB = make_float4(0.f, 0.f, 0.f, 0.f);
        if (b < BB - 1) {
            float4 n = *reinterpret_cast<const float4*>(&outl[((b + 1) * (TT4 + 1) + r) * FF + f0]);
            gB = make_float4(n.x - c.x, n.y - c.y, n.z - c.z, n.w - c.w);
        }
        float4 gT = make_float4(0.f, 0.f, 0.f, 0.f);
        if (t < TT - 1) {
            float4 n = *reinterpret_cast<const float4*>(&outl[(b * (TT4 + 1) + r + 1) * FF + f0]);
            gT = make_float4(n.x - c.x, n.y - c.y, n.z - c.z, n.w - c.w);
        }
        float4 gF;
        gF.x = c.y - c.x; gF.y = c.z - c.y; gF.z = c.w - c.z;
        gF.w = (f0 < FF - 4) ? (outl[(b * (TT4 + 1) + r) * FF + f0 + 4] - c.w) : 0.f;
        float4 nb;
        nb.x = 1.f / (sqrtf(gB.x * gB.x + gT.x * gT.x + gF.x * gF.x) * s + 1.f);
        nb.y = 1.f / (sqrtf(gB.y * gB.y + gT.y * gT.y + gF.y * gF.y) * s + 1.f);
        nb.z = 1.f / (sqrtf(gB.z * gB.z + gT.z * gT.z + gF.z * gF.z) * s + 1.f);
        nb.w = 1.f / (sqrtf(gB.w * gB.w + gT.w * gT.w + gF.w * gF.w) * s + 1.f);
        float4 q0, q1, q2;
        q0.x = (A0[k].x - TAU * gB.x) * nb.x;  q0.y = (A0[k].y - TAU * gB.y) * nb.y;
        q0.z = (A0[k].z - TAU * gB.z) * nb.z;  q0.w = (A0[k].w - TAU * gB.w) * nb.w;
        q1.x = (A1[k].x - TAU * gT.x) * nb.x;  q1.y = (A1[k].y - TAU * gT.y) * nb.y;
        q1.z = (A1[k].z - TAU * gT.z) * nb.z;  q1.w = (A1[k].w - TAU * gT.w) * nb.w;
        q2.x = (A2[k].x - TAU * gF.x) * nb.x;  q2.y = (A2[k].y - TAU * gF.y) * nb.y;
        q2.z = (A2[k].z - TAU * gF.z) * nb.z;  q2.w = (A2[k].w - TAU * gF.w) * nb.w;
        st4(pout + v, q0);
        st4(pout + NV + v, q1);
        st4(pout + 2 * NV + v, q2);
    }
}

__global__ __launch_bounds__(256)
void k_first(const float* __restrict__ x, float* __restrict__ pout,
             const float* __restrict__ lam) {
    const int tid = threadIdx.x;
    const int t0  = blockIdx.x * TT4;
    const float s = TAU / lam[0];
    const int f0 = (tid & 31) * 4;
    const int r  = (tid >> 5) & 3;
    const int b0 = tid >> 7;
    const int t  = t0 + r;
    #pragma unroll
    for (int k = 0; k < 4; ++k) {
        const int b = b0 + 2 * k;
        const int v = b * SB + t * ST + f0;
        float4 X = ld4(x + v);
        float4 gB = make_float4(0.f, 0.f, 0.f, 0.f);
        if (b < BB - 1) {
            float4 n = ld4(x + v + SB);
            gB = make_float4(n.x - X.x, n.y - X.y, n.z - X.z, n.w - X.w);
        }
        float4 gT = make_float4(0.f, 0.f, 0.f, 0.f);
        if (t < TT - 1) {
            float4 n = ld4(x + v + ST);
            gT = make_float4(n.x - X.x, n.y - X.y, n.z - X.z, n.w - X.w);
        }
        float4 gF;
        gF.x = X.y - X.x; gF.y = X.z - X.y; gF.z = X.w - X.z;
        gF.w = (f0 < FF - 4) ? (x[v + 4] - X.w) : 0.f;
        float4 nb;
        nb.x = 1.f / (sqrtf(gB.x * gB.x + gT.x * gT.x + gF.x * gF.x) * s + 1.f);
        nb.y = 1.f / (sqrtf(gB.y * gB.y + gT.y * gT.y + gF.y * gF.y) * s + 1.f);
        nb.z = 1.f / (sqrtf(gB.z * gB.z + gT.z * gT.z + gF.z * gF.z) * s + 1.f);
        nb.w = 1.f / (sqrtf(gB.w * gB.w + gT.w * gT.w + gF.w * gF.w) * s + 1.f);
        float4 q0, q1, q2;
        q0.x = -TAU * gB.x * nb.x;  q0.y = -TAU * gB.y * nb.y;
        q0.z = -TAU * gB.z * nb.z;  q0.w = -TAU * gB.w * nb.w;
        q1.x = -TAU * gT.x * nb.x;  q1.y = -TAU * gT.y * nb.y;
        q1.z = -TAU * gT.z * nb.z;  q1.w = -TAU * gT.w * nb.w;
        q2.x = -TAU * gF.x * nb.x;  q2.y = -TAU * gF.y * nb.y;
        q2.z = -TAU * gF.z * nb.z;  q2.w = -TAU * gF.w * nb.w;
        st4(pout + v, q0);
        st4(pout + NV + v, q1);
        st4(pout + 2 * NV + v, q2);
    }
}

__global__ __launch_bounds__(256)
void k_final(const float* __restrict__ x, const float* __restrict__ pin,
             const float* __restrict__ bias, float* __restrict__ out) {
    const int gid = blockIdx.x * 256 + threadIdx.x;
    const int v = gid * 4;
    const int f0 = v & (FF - 1);
    const int t = (v >> 7) & (TT - 1);
    const int b = v >> 18;
    float4 d0, d1, d2;
    float4 o = compute_out_g(x, pin, pin + NV, pin + 2 * NV, v, b, t, f0, d0, d1, d2);
    float4 bi = ld4(bias + f0);
    o.x += bi.x; o.y += bi.y; o.z += bi.z; o.w += bi.w;
    st4(out + v, o);
}

extern "C" void kernel_launch(void* const* d_in, const int* in_sizes, int n_in,
                              void* d_out, int out_size, void* d_ws, size_t ws_size,
                              hipStream_t stream) {
    const float* x    = (const float*)d_in[0];
    const float* lam  = (const float*)d_in[1];
    const float* bias = (const float*)d_in[2];
    float* out = (float*)d_out;

    // exchange buffers (parity double-buffered): pFirst 2*512*3*1024 f, p1Last 2*512*1024 f
    float* pFirst = (float*)d_ws;
    float* p1Last = pFirst + 2 * NBLK * 3 * PLANE;

    bool coop_ok = false;
    int maxB = 0;
    if (hipOccupancyMaxActiveBlocksPerMultiprocessor(&maxB, (const void*)k_persist,
                                                     NTHR, 0) == hipSuccess &&
        maxB >= 2) {
        void* args[] = { (void*)&x, (void*)&lam, (void*)&bias, (void*)&out,
                         (void*)&pFirst, (void*)&p1Last };
        if (hipLaunchCooperativeKernel((const void*)k_persist, dim3(NBLK), dim3(NTHR),
                                       args, 0, stream) == hipSuccess)
            coop_ok = true;
    }

    if (!coop_ok) {
        // proven R2 multi-kernel path
        float* pA = (float*)d_ws;
        float* pB = pA + 3 * NV;
        const int nblk = TT / TT4;
        k_first<<<nblk, 256, 0, stream>>>(x, pA, lam);
        float* pin = pA;
        float* pout = pB;
        for (int i = 0; i < 28; ++i) {
            k_iter<<<nblk, 256, 0, stream>>>(x, pin, pout, lam);
            float* tmp = pin; pin = pout; pout = tmp;
        }
        k_final<<<NV / 1024, 256, 0, stream>>>(x, pin, bias, out);
    }
}

// Round 4
// 382.025 us; speedup vs baseline: 1.7336x; 1.2755x over previous
//
#include <hip/hip_runtime.h>

// TV Chambolle, image (8, 2048, 128) f32: 29 p-updates + final out = x + div(p) + bias.
// v = b*SB + t*ST + f.
//
// R4: temporal blocking. k_tb fuses HH=4 iterations per launch. Block owns RR=4
// t-rows; loads EE=RR+2*HH=12 rows of p (3 comps, float4/thread) into REGISTERS.
// Lane map: lane = b + 8*fgroup (b fastest) so b+-1 and f+-4 neighbors are in-wave
// shuffles; only fgroup<->wave boundaries go through a 3 KB LDS buffer.
// Update cone: after k fused iters, valid rows [k, EE-k); physical t-edges are
// pinned (boundary conditions are exact), so edge blocks stay correct.
// Launches: k_first (p=0 specialization) + 7 x k_tb (28 iters) + k_final = 9.

#define BB 8
#define TT 2048
#define FF 128
#define NV (BB*TT*FF)        // 2,097,152
#define SB (TT*FF)           // 262144
#define ST FF                // 128
#define RR 4                 // owned t-rows per block
#define NBLK (TT/RR)         // 512
#define HH 4                 // fused iterations per launch
#define EE (RR + 2*HH)       // 12 extended rows

constexpr float TAU = 1.0f / 6.0f;

__device__ __forceinline__ float4 ld4(const float* p) { return *reinterpret_cast<const float4*>(p); }
__device__ __forceinline__ void st4(float* p, const float4& v) { *reinterpret_cast<float4*>(p) = v; }
__device__ __forceinline__ float4 shfl_up4(float4 v, int d) {
    return make_float4(__shfl_up(v.x, d), __shfl_up(v.y, d), __shfl_up(v.z, d), __shfl_up(v.w, d));
}
__device__ __forceinline__ float4 shfl_dn4(float4 v, int d) {
    return make_float4(__shfl_down(v.x, d), __shfl_down(v.y, d), __shfl_down(v.z, d), __shfl_down(v.w, d));
}

__global__ __launch_bounds__(256, 2)
void k_tb(const float* __restrict__ x, const float* __restrict__ pin,
          float* __restrict__ pout, const float* __restrict__ lam) {
    __shared__ float p2b[EE][4][8];    // p2.w at fgroup==7, per [row][wave][b]
    __shared__ float outx[EE][4][8];   // out.x at fgroup==0, per [row][wave][b]

    const int tid = threadIdx.x;
    const int l   = tid & 63;
    const int w   = tid >> 6;          // wave 0..3  -> f range [32w, 32w+32)
    const int b   = l & 7;             // b fastest within wave
    const int fg  = l >> 3;            // f-quad within wave, 0..7
    const int f0  = w * 32 + fg * 4;
    const int tb  = blockIdx.x * RR - HH;
    const int base = b * SB + f0;
    const float s = TAU / lam[0];

    float4 P0[EE], P1[EE], P2[EE], O[EE];

    // ---- load extended p rows into registers (zero-fill out-of-range) ----
    #pragma unroll
    for (int e = 0; e < EE; ++e) {
        const int t = tb + e;
        if (t >= 0 && t < TT) {
            const int v = base + t * ST;
            P0[e] = ld4(pin + v);
            P1[e] = ld4(pin + NV + v);
            P2[e] = ld4(pin + 2 * NV + v);
        } else {
            P0[e] = make_float4(0.f, 0.f, 0.f, 0.f);
            P1[e] = make_float4(0.f, 0.f, 0.f, 0.f);
            P2[e] = make_float4(0.f, 0.f, 0.f, 0.f);
        }
    }

    #pragma unroll
    for (int k = 0; k < HH; ++k) {
        // ---- publish p2 f-boundary values (pre-update state of this iter) ----
        if (fg == 7) {
            #pragma unroll
            for (int e = k; e < EE - k; ++e) p2b[e][w][b] = P2[e].w;
        }
        __syncthreads();

        // ---- out phase: rows e in [k+1, EE-k) ----
        #pragma unroll
        for (int e = k + 1; e < EE - k; ++e) {
            const int t = tb + e;
            if (t >= 0 && t < TT) {
                const float4 X = ld4(x + base + t * ST);
                float4 o;
                o.x = X.x - P0[e].x - P1[e].x - P2[e].x;
                o.y = X.y - P0[e].y - P1[e].y - P2[e].y + P2[e].x;
                o.z = X.z - P0[e].z - P1[e].z - P2[e].z + P2[e].y;
                o.w = X.w - P0[e].w - P1[e].w - P2[e].w + P2[e].z;
                // + p0(b-1): in-wave shuffle (lane-1), masked at b==0
                float4 h0 = shfl_up4(P0[e], 1);
                if (b > 0) { o.x += h0.x; o.y += h0.y; o.z += h0.z; o.w += h0.w; }
                // + p1(t-1): own register, dropped at t==0
                if (t > 0) {
                    o.x += P1[e - 1].x; o.y += P1[e - 1].y;
                    o.z += P1[e - 1].z; o.w += P1[e - 1].w;
                }
                // + p2(f-1): lane-8 .w; fgroup 0 crosses wave -> LDS
                float pw = __shfl_up(P2[e].w, 8);
                if (fg == 0) pw = (w > 0) ? p2b[e][w - 1][b] : 0.0f;
                if (f0 > 0) o.x += pw;
                O[e] = o;
                if (fg == 0) outx[e][w][b] = o.x;
            }
        }
        __syncthreads();

        // ---- update phase: rows e in [k+1, EE-2-k] ----
        #pragma unroll
        for (int e = k + 1; e <= EE - 2 - k; ++e) {
            const int t = tb + e;
            if (t >= 0 && t < TT) {
                const float4 c = O[e];
                float4 gT = make_float4(0.f, 0.f, 0.f, 0.f);
                if (t < TT - 1) {
                    gT.x = O[e + 1].x - c.x; gT.y = O[e + 1].y - c.y;
                    gT.z = O[e + 1].z - c.z; gT.w = O[e + 1].w - c.w;
                }
                const float4 nB = shfl_dn4(c, 1);         // out at b+1 (lane+1)
                float4 gB = make_float4(0.f, 0.f, 0.f, 0.f);
                if (b < BB - 1) {
                    gB.x = nB.x - c.x; gB.y = nB.y - c.y;
                    gB.z = nB.z - c.z; gB.w = nB.w - c.w;
                }
                float nxx = __shfl_down(c.x, 8);          // out.x at f0+4 (lane+8)
                if (fg == 7) nxx = (w < 3) ? outx[e][w + 1][b] : 0.0f;
                float4 gF;
                gF.x = c.y - c.x;
                gF.y = c.z - c.y;
                gF.z = c.w - c.z;
                gF.w = (f0 < FF - 4) ? (nxx - c.w) : 0.f;

                float4 nb;
                nb.x = 1.f / (sqrtf(gB.x * gB.x + gT.x * gT.x + gF.x * gF.x) * s + 1.f);
                nb.y = 1.f / (sqrtf(gB.y * gB.y + gT.y * gT.y + gF.y * gF.y) * s + 1.f);
                nb.z = 1.f / (sqrtf(gB.z * gB.z + gT.z * gT.z + gF.z * gF.z) * s + 1.f);
                nb.w = 1.f / (sqrtf(gB.w * gB.w + gT.w * gT.w + gF.w * gF.w) * s + 1.f);

                P0[e].x = (P0[e].x - TAU * gB.x) * nb.x;
                P0[e].y = (P0[e].y - TAU * gB.y) * nb.y;
                P0[e].z = (P0[e].z - TAU * gB.z) * nb.z;
                P0[e].w = (P0[e].w - TAU * gB.w) * nb.w;
                P1[e].x = (P1[e].x - TAU * gT.x) * nb.x;
                P1[e].y = (P1[e].y - TAU * gT.y) * nb.y;
                P1[e].z = (P1[e].z - TAU * gT.z) * nb.z;
                P1[e].w = (P1[e].w - TAU * gT.w) * nb.w;
                P2[e].x = (P2[e].x - TAU * gF.x) * nb.x;
                P2[e].y = (P2[e].y - TAU * gF.y) * nb.y;
                P2[e].z = (P2[e].z - TAU * gF.z) * nb.z;
                P2[e].w = (P2[e].w - TAU * gF.w) * nb.w;
            }
        }
    }

    // ---- store owned rows e in [HH, HH+RR) ----
    #pragma unroll
    for (int e = HH; e < HH + RR; ++e) {
        const int v = base + (tb + e) * ST;
        st4(pout + v, P0[e]);
        st4(pout + NV + v, P1[e]);
        st4(pout + 2 * NV + v, P2[e]);
    }
}

// ---- first iteration (p=0 -> out = x), proven in R2 ----
__global__ __launch_bounds__(256)
void k_first(const float* __restrict__ x, float* __restrict__ pout,
             const float* __restrict__ lam) {
    const int tid = threadIdx.x;
    const int t0  = blockIdx.x * 4;
    const float s = TAU / lam[0];
    const int f0 = (tid & 31) * 4;
    const int r  = (tid >> 5) & 3;
    const int b0 = tid >> 7;
    const int t  = t0 + r;
    #pragma unroll
    for (int k = 0; k < 4; ++k) {
        const int b = b0 + 2 * k;
        const int v = b * SB + t * ST + f0;
        float4 X = ld4(x + v);
        float4 gB = make_float4(0.f, 0.f, 0.f, 0.f);
        if (b < BB - 1) {
            float4 n = ld4(x + v + SB);
            gB = make_float4(n.x - X.x, n.y - X.y, n.z - X.z, n.w - X.w);
        }
        float4 gT = make_float4(0.f, 0.f, 0.f, 0.f);
        if (t < TT - 1) {
            float4 n = ld4(x + v + ST);
            gT = make_float4(n.x - X.x, n.y - X.y, n.z - X.z, n.w - X.w);
        }
        float4 gF;
        gF.x = X.y - X.x; gF.y = X.z - X.y; gF.z = X.w - X.z;
        gF.w = (f0 < FF - 4) ? (x[v + 4] - X.w) : 0.f;
        float4 nb;
        nb.x = 1.f / (sqrtf(gB.x * gB.x + gT.x * gT.x + gF.x * gF.x) * s + 1.f);
        nb.y = 1.f / (sqrtf(gB.y * gB.y + gT.y * gT.y + gF.y * gF.y) * s + 1.f);
        nb.z = 1.f / (sqrtf(gB.z * gB.z + gT.z * gT.z + gF.z * gF.z) * s + 1.f);
        nb.w = 1.f / (sqrtf(gB.w * gB.w + gT.w * gT.w + gF.w * gF.w) * s + 1.f);
        float4 q0, q1, q2;
        q0.x = -TAU * gB.x * nb.x;  q0.y = -TAU * gB.y * nb.y;
        q0.z = -TAU * gB.z * nb.z;  q0.w = -TAU * gB.w * nb.w;
        q1.x = -TAU * gT.x * nb.x;  q1.y = -TAU * gT.y * nb.y;
        q1.z = -TAU * gT.z * nb.z;  q1.w = -TAU * gT.w * nb.w;
        q2.x = -TAU * gF.x * nb.x;  q2.y = -TAU * gF.y * nb.y;
        q2.z = -TAU * gF.z * nb.z;  q2.w = -TAU * gF.w * nb.w;
        st4(pout + v, q0);
        st4(pout + NV + v, q1);
        st4(pout + 2 * NV + v, q2);
    }
}

// ---- final: out = x + div(p) + bias, proven in R2 ----
__global__ __launch_bounds__(256)
void k_final(const float* __restrict__ x, const float* __restrict__ pin,
             const float* __restrict__ bias, float* __restrict__ out) {
    const int gid = blockIdx.x * 256 + threadIdx.x;
    const int v = gid * 4;
    const int f0 = v & (FF - 1);
    const int t = (v >> 7) & (TT - 1);
    const int b = v >> 18;
    const float* p0 = pin;
    const float* p1 = pin + NV;
    const float* p2 = pin + 2 * NV;
    float4 X = ld4(x + v);
    float4 a0 = ld4(p0 + v), a1 = ld4(p1 + v), a2 = ld4(p2 + v);
    float ox = X.x - a0.x - a1.x - a2.x;
    float oy = X.y - a0.y - a1.y - a2.y + a2.x;
    float oz = X.z - a0.z - a1.z - a2.z + a2.y;
    float ow = X.w - a0.w - a1.w - a2.w + a2.z;
    if (b > 0) { float4 h = ld4(p0 + v - SB); ox += h.x; oy += h.y; oz += h.z; ow += h.w; }
    if (t > 0) { float4 h = ld4(p1 + v - ST); ox += h.x; oy += h.y; oz += h.z; ow += h.w; }
    if (f0 > 0) ox += p2[v - 1];
    float4 bi = ld4(bias + f0);
    st4(out + v, make_float4(ox + bi.x, oy + bi.y, oz + bi.z, ow + bi.w));
}

extern "C" void kernel_launch(void* const* d_in, const int* in_sizes, int n_in,
                              void* d_out, int out_size, void* d_ws, size_t ws_size,
                              hipStream_t stream) {
    const float* x    = (const float*)d_in[0];
    const float* lam  = (const float*)d_in[1];
    const float* bias = (const float*)d_in[2];
    float* out = (float*)d_out;

    float* pA = (float*)d_ws;
    float* pB = pA + 3 * NV;

    // iteration 1 (p=0 specialization)
    k_first<<<NBLK, 256, 0, stream>>>(x, pA, lam);
    // 7 fused launches x 4 iterations = 28 more -> 29 total
    float* pin = pA;
    float* pout = pB;
    for (int i = 0; i < 7; ++i) {
        k_tb<<<NBLK, 256, 0, stream>>>(x, pin, pout, lam);
        float* tmp = pin; pin = pout; pout = tmp;
    }
    k_final<<<NV / 1024, 256, 0, stream>>>(x, pin, bias, out);
}